// Round 1
// baseline (720.865 us; speedup 1.0000x reference)
//
#include <hip/hip_runtime.h>

#define N_NODES   100000
#define N_EDGES   1600000
#define N_FEAT    128
#define HIDDEN    64
#define NUM_GRAPHS 64

// ---------------------------------------------------------------------------
// K1: h = x @ W   (x: [N,128], W: [128,64], h: [N,64])
// Block = 256 threads: 4 rows x 64 cols per iteration. W staged in LDS (32 KB),
// x rows staged in LDS (2 KB). Grid-stride so W is loaded once per block.
// ---------------------------------------------------------------------------
__global__ __launch_bounds__(256) void gemm_xw(const float* __restrict__ x,
                                               const float* __restrict__ W,
                                               float* __restrict__ h) {
    __shared__ float Ws[N_FEAT * HIDDEN];   // 32 KB
    __shared__ float xs[4][N_FEAT];         // 2 KB
    const int tid = threadIdx.x;
    for (int i = tid; i < N_FEAT * HIDDEN; i += 256) Ws[i] = W[i];
    const int col = tid & 63;
    const int r   = tid >> 6;
    for (int base = blockIdx.x * 4; base < N_NODES; base += gridDim.x * 4) {
        __syncthreads();   // protect xs from previous iteration (also fences Ws load 1st time)
        for (int i = tid; i < 4 * N_FEAT; i += 256) {
            const int rr = i >> 7, k = i & 127;
            const int row = base + rr;
            xs[rr][k] = (row < N_NODES) ? x[(size_t)row * N_FEAT + k] : 0.f;
        }
        __syncthreads();
        const int row = base + r;
        if (row < N_NODES) {
            float acc = 0.f;
#pragma unroll
            for (int k = 0; k < N_FEAT; ++k)
                acc = fmaf(xs[r][k], Ws[k * HIDDEN + col], acc);
            h[(size_t)row * HIDDEN + col] = acc;
        }
    }
}

// ---------------------------------------------------------------------------
// K2: deg[dst] += 1 per edge (deg pre-zeroed; self-loop handled as +1 later)
// ---------------------------------------------------------------------------
__global__ __launch_bounds__(256) void deg_kernel(const int* __restrict__ ei,
                                                  int* __restrict__ deg) {
    const int e = blockIdx.x * 256 + threadIdx.x;
    if (e < N_EDGES) atomicAdd(&deg[ei[N_EDGES + e]], 1);
}

// ---------------------------------------------------------------------------
// K3: dis[i] = rsqrt(deg[i] + 1)   (+1 = self loop; always > 0)
// ---------------------------------------------------------------------------
__global__ __launch_bounds__(256) void dis_kernel(const int* __restrict__ deg,
                                                  float* __restrict__ dis) {
    const int i = blockIdx.x * 256 + threadIdx.x;
    if (i < N_NODES) dis[i] = rsqrtf((float)deg[i] + 1.0f);
}

// ---------------------------------------------------------------------------
// K4: self-loop init: agg[i][c] = h[i][c] * dis[i]^2
// ---------------------------------------------------------------------------
__global__ __launch_bounds__(256) void selfloop_kernel(const float* __restrict__ h,
                                                       const float* __restrict__ dis,
                                                       float* __restrict__ agg) {
    const size_t t = (size_t)blockIdx.x * 256 + threadIdx.x;
    if (t < (size_t)N_NODES * HIDDEN) {
        const int i = (int)(t >> 6);
        const float d = dis[i];
        agg[t] = h[t] * d * d;
    }
}

// ---------------------------------------------------------------------------
// K5: edge scatter: agg[dst][c] += h[src][c] * dis[src]*dis[dst]
// 64 lanes per edge (one full cache-line gather + one contiguous atomic burst)
// ---------------------------------------------------------------------------
__global__ __launch_bounds__(256) void edge_scatter(const int* __restrict__ ei,
                                                    const float* __restrict__ h,
                                                    const float* __restrict__ dis,
                                                    float* __restrict__ agg) {
    const long long t = (long long)blockIdx.x * 256 + threadIdx.x;
    const long long e = t >> 6;
    const int c = (int)(t & 63);
    if (e < N_EDGES) {
        const int s = ei[e];
        const int d = ei[N_EDGES + e];
        const float norm = dis[s] * dis[d];
        atomicAdd(&agg[(size_t)d * HIDDEN + c], h[(size_t)s * HIDDEN + c] * norm);
    }
}

// ---------------------------------------------------------------------------
// K6: global_add_pool. batch sorted -> block g finds its node range by binary
// search, sums relu(agg + b) without atomics.
// ---------------------------------------------------------------------------
__device__ __forceinline__ int lower_bound_i(const int* __restrict__ arr, int n, int val) {
    int lo = 0, hi = n;
    while (lo < hi) {
        const int mid = (lo + hi) >> 1;
        if (arr[mid] < val) lo = mid + 1; else hi = mid;
    }
    return lo;
}

__global__ __launch_bounds__(256) void pool_kernel(const float* __restrict__ agg,
                                                   const float* __restrict__ bias,
                                                   const int* __restrict__ batch,
                                                   float* __restrict__ u) {
    const int g = blockIdx.x;
    __shared__ int s_lo, s_hi;
    __shared__ float part[4][HIDDEN];
    if (threadIdx.x == 0) {
        s_lo = lower_bound_i(batch, N_NODES, g);
        s_hi = lower_bound_i(batch, N_NODES, g + 1);
    }
    __syncthreads();
    const int c = threadIdx.x & 63;
    const int r = threadIdx.x >> 6;
    const float bc = bias[c];
    float acc = 0.f;
    for (int node = s_lo + r; node < s_hi; node += 4)
        acc += fmaxf(agg[(size_t)node * HIDDEN + c] + bc, 0.f);
    part[r][c] = acc;
    __syncthreads();
    if (r == 0)
        u[g * HIDDEN + c] = part[0][c] + part[1][c] + part[2][c] + part[3][c];
}

// ---------------------------------------------------------------------------
// K7: out[g] = relu(u[g] @ W1 + b1) @ W2 + b2    (u: [64,64], W1: [64,16])
// ---------------------------------------------------------------------------
__global__ __launch_bounds__(64) void mlp_kernel(const float* __restrict__ u,
                                                 const float* __restrict__ W1,
                                                 const float* __restrict__ b1,
                                                 const float* __restrict__ W2,
                                                 const float* __restrict__ b2,
                                                 float* __restrict__ out) {
    __shared__ float W1s[HIDDEN * 16];
    __shared__ float W2s[16];
    __shared__ float b1s[16];
    const int t = threadIdx.x;
    for (int i = t; i < HIDDEN * 16; i += 64) W1s[i] = W1[i];
    if (t < 16) { W2s[t] = W2[t]; b1s[t] = b1[t]; }
    __syncthreads();
    if (t < NUM_GRAPHS) {
        float uu[HIDDEN];
#pragma unroll
        for (int k = 0; k < HIDDEN; ++k) uu[k] = u[t * HIDDEN + k];
        float o = b2[0];
#pragma unroll
        for (int j = 0; j < 16; ++j) {
            float s = b1s[j];
#pragma unroll
            for (int k = 0; k < HIDDEN; ++k) s = fmaf(uu[k], W1s[k * 16 + j], s);
            o = fmaf(fmaxf(s, 0.f), W2s[j], o);
        }
        out[t] = o;
    }
}

// ---------------------------------------------------------------------------
extern "C" void kernel_launch(void* const* d_in, const int* in_sizes, int n_in,
                              void* d_out, int out_size, void* d_ws, size_t ws_size,
                              hipStream_t stream) {
    const float* x  = (const float*)d_in[0];
    const float* W  = (const float*)d_in[1];
    const float* b  = (const float*)d_in[2];
    const float* W1 = (const float*)d_in[3];
    const float* b1 = (const float*)d_in[4];
    const float* W2 = (const float*)d_in[5];
    const float* b2 = (const float*)d_in[6];
    const int*   ei = (const int*)d_in[7];     // [2, E] flat: src = ei[e], dst = ei[E+e]
    const int* batch = (const int*)d_in[8];    // [N], sorted
    float* out = (float*)d_out;

    // workspace layout (all fp32 unless noted):
    //   h   : N*64           = 25.6 MB
    //   agg : N*64           = 25.6 MB
    //   deg : N (int)        = 0.4 MB
    //   dis : N              = 0.4 MB
    //   u   : 64*64          = 16 KB
    float* h   = (float*)d_ws;
    float* agg = h + (size_t)N_NODES * HIDDEN;
    int*   deg = (int*)(agg + (size_t)N_NODES * HIDDEN);
    float* dis = (float*)(deg + N_NODES);
    float* u   = dis + N_NODES;

    hipMemsetAsync(deg, 0, N_NODES * sizeof(int), stream);

    gemm_xw<<<2048, 256, 0, stream>>>(x, W, h);
    deg_kernel<<<(N_EDGES + 255) / 256, 256, 0, stream>>>(ei, deg);
    dis_kernel<<<(N_NODES + 255) / 256, 256, 0, stream>>>(deg, dis);
    selfloop_kernel<<<(N_NODES * HIDDEN + 255) / 256, 256, 0, stream>>>(h, dis, agg);
    edge_scatter<<<(int)(((long long)N_EDGES * 64 + 255) / 256), 256, 0, stream>>>(ei, h, dis, agg);
    pool_kernel<<<NUM_GRAPHS, 256, 0, stream>>>(agg, b, batch, u);
    mlp_kernel<<<1, 64, 0, stream>>>(u, W1, b1, W2, b2, out);
}

// Round 2
// 496.471 us; speedup vs baseline: 1.4520x; 1.4520x over previous
//
#include <hip/hip_runtime.h>

#define N_NODES   100000
#define N_EDGES   1600000
#define N_FEAT    128
#define HIDDEN    64
#define NUM_GRAPHS 64
#define SCAN_BLOCKS ((N_NODES + 255) / 256)   // 391

// ---------------------------------------------------------------------------
// K1: h = x @ W   (x: [N,128], W: [128,64], h: [N,64])
// W transposed in LDS (row padded 128->132 floats) so the k-loop reads both
// operands with ds_read_b128. 8 rows/block/iter, grid-stride.
// ---------------------------------------------------------------------------
__global__ __launch_bounds__(256) void gemm_xw(const float* __restrict__ x,
                                               const float* __restrict__ W,
                                               float* __restrict__ h) {
    __shared__ float Wt[HIDDEN][N_FEAT + 4];   // 33.8 KB, pad 4 breaks bank aliasing
    __shared__ float xs[8][N_FEAT];            // 4 KB
    const int tid = threadIdx.x;
    for (int i = tid; i < N_FEAT * HIDDEN; i += 256) {
        const int k = i >> 6, c = i & 63;      // W is [k][c]
        Wt[c][k] = W[i];
    }
    const int col = tid & 63;
    const int r   = tid >> 6;                  // wave id 0..3
    for (int base = blockIdx.x * 8; base < N_NODES; base += gridDim.x * 8) {
        __syncthreads();
        {   // stage 8 rows = 1024 floats via 256 x float4
            const int idx = tid * 4;
            const int rr = idx >> 7, k = idx & 127;
            const int row = base + rr;
            float4 v = make_float4(0.f, 0.f, 0.f, 0.f);
            if (row < N_NODES) v = *(const float4*)&x[(size_t)row * N_FEAT + k];
            *(float4*)&xs[rr][k] = v;
        }
        __syncthreads();
#pragma unroll
        for (int q = 0; q < 2; ++q) {          // wave r -> rows r*2, r*2+1
            const int rr = r * 2 + q;
            const int row = base + rr;
            if (row >= N_NODES) continue;
            float a0 = 0.f, a1 = 0.f, a2 = 0.f, a3 = 0.f;
#pragma unroll
            for (int k = 0; k < N_FEAT; k += 4) {
                const float4 xv = *(const float4*)&xs[rr][k];
                const float4 wv = *(const float4*)&Wt[col][k];
                a0 = fmaf(xv.x, wv.x, a0);
                a1 = fmaf(xv.y, wv.y, a1);
                a2 = fmaf(xv.z, wv.z, a2);
                a3 = fmaf(xv.w, wv.w, a3);
            }
            h[(size_t)row * HIDDEN + col] = (a0 + a1) + (a2 + a3);
        }
    }
}

// ---------------------------------------------------------------------------
// K2: deg[dst] += 1 per edge (deg pre-zeroed; +1 self-loop applied in dis)
// ---------------------------------------------------------------------------
__global__ __launch_bounds__(256) void deg_kernel(const int* __restrict__ ei,
                                                  int* __restrict__ deg) {
    const int e = blockIdx.x * 256 + threadIdx.x;
    if (e < N_EDGES) atomicAdd(&deg[ei[N_EDGES + e]], 1);
}

// ---------------------------------------------------------------------------
// K3: dis[i] = rsqrt(deg[i] + 1)
// ---------------------------------------------------------------------------
__global__ __launch_bounds__(256) void dis_kernel(const int* __restrict__ deg,
                                                  float* __restrict__ dis) {
    const int i = blockIdx.x * 256 + threadIdx.x;
    if (i < N_NODES) dis[i] = rsqrtf((float)deg[i] + 1.0f);
}

// ---------------------------------------------------------------------------
// Scan (exclusive prefix sum of deg -> row_ptr), 3 small kernels.
// ---------------------------------------------------------------------------
__global__ __launch_bounds__(256) void scan1(const int* __restrict__ deg,
                                             int* __restrict__ row_ptr,
                                             int* __restrict__ bsum) {
    __shared__ int s[256];
    const int t = threadIdx.x;
    const int i = blockIdx.x * 256 + t;
    const int v = (i < N_NODES) ? deg[i] : 0;
    s[t] = v;
    __syncthreads();
    for (int off = 1; off < 256; off <<= 1) {
        const int add = (t >= off) ? s[t - off] : 0;
        __syncthreads();
        s[t] += add;
        __syncthreads();
    }
    if (i < N_NODES) row_ptr[i] = s[t] - v;   // exclusive
    if (t == 255) bsum[blockIdx.x] = s[255];
}

__global__ __launch_bounds__(512) void scan2(const int* __restrict__ bsum,
                                             int* __restrict__ boff) {
    __shared__ int s[512];
    const int t = threadIdx.x;
    const int v = (t < SCAN_BLOCKS) ? bsum[t] : 0;
    s[t] = v;
    __syncthreads();
    for (int off = 1; off < 512; off <<= 1) {
        const int add = (t >= off) ? s[t - off] : 0;
        __syncthreads();
        s[t] += add;
        __syncthreads();
    }
    if (t < SCAN_BLOCKS) boff[t] = s[t] - v;  // exclusive
}

__global__ __launch_bounds__(256) void scan3(int* __restrict__ row_ptr,
                                             const int* __restrict__ boff,
                                             int* __restrict__ next) {
    const int i = blockIdx.x * 256 + threadIdx.x;
    if (i < N_NODES) {
        const int r = row_ptr[i] + boff[i >> 8];
        row_ptr[i] = r;
        next[i] = r;
    }
}

// ---------------------------------------------------------------------------
// K4: CSR build — scatter edges into dst-sorted order, precompute norm.
// After this kernel, next[i] == row_end[i].
// ---------------------------------------------------------------------------
__global__ __launch_bounds__(256) void csr_build(const int* __restrict__ ei,
                                                 const float* __restrict__ dis,
                                                 int* __restrict__ next,
                                                 int* __restrict__ srcs,
                                                 float* __restrict__ wts) {
    const int e = blockIdx.x * 256 + threadIdx.x;
    if (e < N_EDGES) {
        const int s = ei[e];
        const int d = ei[N_EDGES + e];
        const int pos = atomicAdd(&next[d], 1);
        srcs[pos] = s;
        wts[pos] = dis[s] * dis[d];
    }
}

// ---------------------------------------------------------------------------
// K5: per-node gather-aggregate. One wave per node, lane = column.
// hn[node][c] = relu( sum_{e in-edges} h[src_e][c]*w_e + h[node][c]*dis^2 + b[c] )
// ---------------------------------------------------------------------------
__global__ __launch_bounds__(256) void agg_kernel(const int* __restrict__ row_ptr,
                                                  const int* __restrict__ row_end,
                                                  const int* __restrict__ srcs,
                                                  const float* __restrict__ wts,
                                                  const float* __restrict__ h,
                                                  const float* __restrict__ dis,
                                                  const float* __restrict__ bias,
                                                  float* __restrict__ hn) {
    const int node = blockIdx.x * 4 + (threadIdx.x >> 6);
    if (node >= N_NODES) return;
    const int lane = threadIdx.x & 63;
    const int beg = row_ptr[node];
    const int end = row_end[node];
    const float dn = dis[node];
    float a0 = h[(size_t)node * HIDDEN + lane] * dn * dn;   // self-loop
    float a1 = 0.f, a2 = 0.f, a3 = 0.f;
    for (int j0 = beg; j0 < end; j0 += 64) {
        const int n = min(64, end - j0);
        int s = 0; float w = 0.f;
        if (lane < n) { s = srcs[j0 + lane]; w = wts[j0 + lane]; }
        int i = 0;
        for (; i + 4 <= n; i += 4) {
            const int s0 = __shfl(s, i),     s1 = __shfl(s, i + 1);
            const int s2 = __shfl(s, i + 2), s3 = __shfl(s, i + 3);
            const float w0 = __shfl(w, i),     w1 = __shfl(w, i + 1);
            const float w2 = __shfl(w, i + 2), w3 = __shfl(w, i + 3);
            const float v0 = h[(size_t)s0 * HIDDEN + lane];
            const float v1 = h[(size_t)s1 * HIDDEN + lane];
            const float v2 = h[(size_t)s2 * HIDDEN + lane];
            const float v3 = h[(size_t)s3 * HIDDEN + lane];
            a0 = fmaf(v0, w0, a0);
            a1 = fmaf(v1, w1, a1);
            a2 = fmaf(v2, w2, a2);
            a3 = fmaf(v3, w3, a3);
        }
        for (; i < n; ++i) {
            const int si = __shfl(s, i);
            const float wi = __shfl(w, i);
            a0 = fmaf(h[(size_t)si * HIDDEN + lane], wi, a0);
        }
    }
    const float acc = (a0 + a1) + (a2 + a3);
    hn[(size_t)node * HIDDEN + lane] = fmaxf(acc + bias[lane], 0.f);
}

// ---------------------------------------------------------------------------
// K6: global_add_pool (batch sorted -> binary search range, no atomics).
// bias/relu already applied in agg_kernel.
// ---------------------------------------------------------------------------
__device__ __forceinline__ int lower_bound_i(const int* __restrict__ arr, int n, int val) {
    int lo = 0, hi = n;
    while (lo < hi) {
        const int mid = (lo + hi) >> 1;
        if (arr[mid] < val) lo = mid + 1; else hi = mid;
    }
    return lo;
}

__global__ __launch_bounds__(256) void pool_kernel(const float* __restrict__ hn,
                                                   const int* __restrict__ batch,
                                                   float* __restrict__ u) {
    const int g = blockIdx.x;
    __shared__ int s_lo, s_hi;
    __shared__ float part[4][HIDDEN];
    if (threadIdx.x == 0) {
        s_lo = lower_bound_i(batch, N_NODES, g);
        s_hi = lower_bound_i(batch, N_NODES, g + 1);
    }
    __syncthreads();
    const int c = threadIdx.x & 63;
    const int r = threadIdx.x >> 6;
    float acc = 0.f;
    for (int node = s_lo + r; node < s_hi; node += 4)
        acc += hn[(size_t)node * HIDDEN + c];
    part[r][c] = acc;
    __syncthreads();
    if (r == 0)
        u[g * HIDDEN + c] = part[0][c] + part[1][c] + part[2][c] + part[3][c];
}

// ---------------------------------------------------------------------------
// K7: out[g] = relu(u[g] @ W1 + b1) @ W2 + b2
// ---------------------------------------------------------------------------
__global__ __launch_bounds__(64) void mlp_kernel(const float* __restrict__ u,
                                                 const float* __restrict__ W1,
                                                 const float* __restrict__ b1,
                                                 const float* __restrict__ W2,
                                                 const float* __restrict__ b2,
                                                 float* __restrict__ out) {
    __shared__ float W1s[HIDDEN * 16];
    __shared__ float W2s[16];
    __shared__ float b1s[16];
    const int t = threadIdx.x;
    for (int i = t; i < HIDDEN * 16; i += 64) W1s[i] = W1[i];
    if (t < 16) { W2s[t] = W2[t]; b1s[t] = b1[t]; }
    __syncthreads();
    if (t < NUM_GRAPHS) {
        float uu[HIDDEN];
#pragma unroll
        for (int k = 0; k < HIDDEN; ++k) uu[k] = u[t * HIDDEN + k];
        float o = b2[0];
#pragma unroll
        for (int j = 0; j < 16; ++j) {
            float s = b1s[j];
#pragma unroll
            for (int k = 0; k < HIDDEN; ++k) s = fmaf(uu[k], W1s[k * 16 + j], s);
            o = fmaf(fmaxf(s, 0.f), W2s[j], o);
        }
        out[t] = o;
    }
}

// ---------------------------------------------------------------------------
extern "C" void kernel_launch(void* const* d_in, const int* in_sizes, int n_in,
                              void* d_out, int out_size, void* d_ws, size_t ws_size,
                              hipStream_t stream) {
    const float* x  = (const float*)d_in[0];
    const float* W  = (const float*)d_in[1];
    const float* b  = (const float*)d_in[2];
    const float* W1 = (const float*)d_in[3];
    const float* b1 = (const float*)d_in[4];
    const float* W2 = (const float*)d_in[5];
    const float* b2 = (const float*)d_in[6];
    const int*   ei = (const int*)d_in[7];     // [2, E] flat: src = ei[e], dst = ei[E+e]
    const int* batch = (const int*)d_in[8];    // [N], sorted
    float* out = (float*)d_out;

    // workspace layout:
    //   h       N*64 f32   25.6 MB
    //   hn      N*64 f32   25.6 MB
    //   srcs    E   int     6.4 MB
    //   wts     E   f32     6.4 MB
    //   deg     N   int     0.4 MB
    //   dis     N   f32     0.4 MB
    //   row_ptr N   int     0.4 MB
    //   next    N   int     0.4 MB
    //   bsum/boff/u         tiny
    float* h    = (float*)d_ws;
    float* hn   = h + (size_t)N_NODES * HIDDEN;
    int*   srcs = (int*)(hn + (size_t)N_NODES * HIDDEN);
    float* wts  = (float*)(srcs + N_EDGES);
    int*   deg  = (int*)(wts + N_EDGES);
    float* dis  = (float*)(deg + N_NODES);
    int*   row_ptr = (int*)(dis + N_NODES);
    int*   next    = row_ptr + N_NODES;
    int*   bsum    = next + N_NODES;
    int*   boff    = bsum + 512;
    float* u       = (float*)(boff + 512);

    hipMemsetAsync(deg, 0, N_NODES * sizeof(int), stream);

    gemm_xw<<<2048, 256, 0, stream>>>(x, W, h);
    deg_kernel<<<(N_EDGES + 255) / 256, 256, 0, stream>>>(ei, deg);
    dis_kernel<<<SCAN_BLOCKS, 256, 0, stream>>>(deg, dis);
    scan1<<<SCAN_BLOCKS, 256, 0, stream>>>(deg, row_ptr, bsum);
    scan2<<<1, 512, 0, stream>>>(bsum, boff);
    scan3<<<SCAN_BLOCKS, 256, 0, stream>>>(row_ptr, boff, next);
    csr_build<<<(N_EDGES + 255) / 256, 256, 0, stream>>>(ei, dis, next, srcs, wts);
    agg_kernel<<<(N_NODES + 3) / 4, 256, 0, stream>>>(row_ptr, next, srcs, wts, h, dis, b, hn);
    pool_kernel<<<NUM_GRAPHS, 256, 0, stream>>>(hn, batch, u);
    mlp_kernel<<<1, 64, 0, stream>>>(u, W1, b1, W2, b2, out);
}

// Round 3
// 405.528 us; speedup vs baseline: 1.7776x; 1.2243x over previous
//
#include <hip/hip_runtime.h>

#define N_NODES   100000
#define N_EDGES   1600000
#define N_FEAT    128
#define HIDDEN    64
#define NUM_GRAPHS 64
#define SCAN_BLOCKS ((N_NODES + 255) / 256)   // 391
#define XPAD 130                              // LDS row stride: bank=(2r+k)%32 -> 2-way (free)

// ---------------------------------------------------------------------------
// K1: h = x @ W. lane = row (64 rows/block tile), wave w computes cols
// [16w,16w+16). x staged in LDS (pad 130); W read via wave-uniform scalar
// loads -> SGPR operand of v_fma. K-loop does 1 cheap LDS read + 16 FMAs.
// ---------------------------------------------------------------------------
__global__ __launch_bounds__(256) void gemm_xw(const float* __restrict__ x,
                                               const float* __restrict__ W,
                                               float* __restrict__ h) {
    __shared__ float xs[64 * XPAD];            // 33.3 KB
    const int tid  = threadIdx.x;
    const int lane = tid & 63;
    const int wid  = __builtin_amdgcn_readfirstlane(tid >> 6);  // force wave-uniform
    const int c0   = wid * 16;
    const int base = blockIdx.x * 64;

    // stage 64 rows x 128 floats, coalesced float4 global reads
#pragma unroll
    for (int j = 0; j < 8; ++j) {
        const int flat = (tid + j * 256) * 4;
        const int r = flat >> 7, k = flat & 127;
        const int row = base + r;
        float4 v = make_float4(0.f, 0.f, 0.f, 0.f);
        if (row < N_NODES) v = *(const float4*)&x[(size_t)row * N_FEAT + k];
        xs[r * XPAD + k + 0] = v.x;
        xs[r * XPAD + k + 1] = v.y;
        xs[r * XPAD + k + 2] = v.z;
        xs[r * XPAD + k + 3] = v.w;
    }
    __syncthreads();

    float acc[16];
#pragma unroll
    for (int c = 0; c < 16; ++c) acc[c] = 0.f;

    const float* __restrict__ Wp = W + c0;     // wave-uniform pointer
#pragma unroll 4
    for (int k = 0; k < N_FEAT; ++k) {
        const float xv = xs[lane * XPAD + k];
#pragma unroll
        for (int c = 0; c < 16; ++c)
            acc[c] = fmaf(xv, Wp[k * HIDDEN + c], acc[c]);
    }

    const int row = base + lane;
    if (row < N_NODES) {
        float* hp = &h[(size_t)row * HIDDEN + c0];
#pragma unroll
        for (int c = 0; c < 16; c += 4)
            *(float4*)&hp[c] = make_float4(acc[c], acc[c + 1], acc[c + 2], acc[c + 3]);
    }
}

// ---------------------------------------------------------------------------
// K2: deg[dst] += 1 per edge (deg pre-zeroed; +1 self-loop applied in dis)
// ---------------------------------------------------------------------------
__global__ __launch_bounds__(256) void deg_kernel(const int* __restrict__ ei,
                                                  int* __restrict__ deg) {
    const int e = blockIdx.x * 256 + threadIdx.x;
    if (e < N_EDGES) atomicAdd(&deg[ei[N_EDGES + e]], 1);
}

// ---------------------------------------------------------------------------
// K3: dis[i] = rsqrt(deg[i] + 1)
// ---------------------------------------------------------------------------
__global__ __launch_bounds__(256) void dis_kernel(const int* __restrict__ deg,
                                                  float* __restrict__ dis) {
    const int i = blockIdx.x * 256 + threadIdx.x;
    if (i < N_NODES) dis[i] = rsqrtf((float)deg[i] + 1.0f);
}

// ---------------------------------------------------------------------------
// Scan (exclusive prefix sum of deg -> row_ptr), 3 small kernels.
// ---------------------------------------------------------------------------
__global__ __launch_bounds__(256) void scan1(const int* __restrict__ deg,
                                             int* __restrict__ row_ptr,
                                             int* __restrict__ bsum) {
    __shared__ int s[256];
    const int t = threadIdx.x;
    const int i = blockIdx.x * 256 + t;
    const int v = (i < N_NODES) ? deg[i] : 0;
    s[t] = v;
    __syncthreads();
    for (int off = 1; off < 256; off <<= 1) {
        const int add = (t >= off) ? s[t - off] : 0;
        __syncthreads();
        s[t] += add;
        __syncthreads();
    }
    if (i < N_NODES) row_ptr[i] = s[t] - v;   // exclusive
    if (t == 255) bsum[blockIdx.x] = s[255];
}

__global__ __launch_bounds__(512) void scan2(const int* __restrict__ bsum,
                                             int* __restrict__ boff) {
    __shared__ int s[512];
    const int t = threadIdx.x;
    const int v = (t < SCAN_BLOCKS) ? bsum[t] : 0;
    s[t] = v;
    __syncthreads();
    for (int off = 1; off < 512; off <<= 1) {
        const int add = (t >= off) ? s[t - off] : 0;
        __syncthreads();
        s[t] += add;
        __syncthreads();
    }
    if (t < SCAN_BLOCKS) boff[t] = s[t] - v;  // exclusive
}

__global__ __launch_bounds__(256) void scan3(int* __restrict__ row_ptr,
                                             const int* __restrict__ boff,
                                             int* __restrict__ next) {
    const int i = blockIdx.x * 256 + threadIdx.x;
    if (i < N_NODES) {
        const int r = row_ptr[i] + boff[i >> 8];
        row_ptr[i] = r;
        next[i] = r;
    }
}

// ---------------------------------------------------------------------------
// K4: CSR build — only the src index is scattered (one dirty line per edge);
// the edge weight is recomputed in agg from dis.
// ---------------------------------------------------------------------------
__global__ __launch_bounds__(256) void csr_build(const int* __restrict__ ei,
                                                 int* __restrict__ next,
                                                 int* __restrict__ srcs) {
    const int e = blockIdx.x * 256 + threadIdx.x;
    if (e < N_EDGES) {
        const int s = ei[e];
        const int d = ei[N_EDGES + e];
        const int pos = atomicAdd(&next[d], 1);
        srcs[pos] = s;
    }
}

// ---------------------------------------------------------------------------
// K5: per-node gather-aggregate. One wave per node, lane = column.
// hn[node][c] = relu( sum_e h[src_e][c]*dis[src_e]*dn + h[node][c]*dn^2 + b[c] )
// ---------------------------------------------------------------------------
__global__ __launch_bounds__(256) void agg_kernel(const int* __restrict__ row_ptr,
                                                  const int* __restrict__ row_end,
                                                  const int* __restrict__ srcs,
                                                  const float* __restrict__ h,
                                                  const float* __restrict__ dis,
                                                  const float* __restrict__ bias,
                                                  float* __restrict__ hn) {
    const int node = blockIdx.x * 4 + (threadIdx.x >> 6);
    if (node >= N_NODES) return;
    const int lane = threadIdx.x & 63;
    const int beg = row_ptr[node];
    const int end = row_end[node];
    const float dn = dis[node];
    float a0 = h[(size_t)node * HIDDEN + lane] * dn * dn;   // self-loop
    float a1 = 0.f, a2 = 0.f, a3 = 0.f;
    for (int j0 = beg; j0 < end; j0 += 64) {
        const int n = min(64, end - j0);
        int s = 0; float w = 0.f;
        if (lane < n) { s = srcs[j0 + lane]; w = dis[s] * dn; }
        int i = 0;
        for (; i + 4 <= n; i += 4) {
            const int s0 = __shfl(s, i),     s1 = __shfl(s, i + 1);
            const int s2 = __shfl(s, i + 2), s3 = __shfl(s, i + 3);
            const float w0 = __shfl(w, i),     w1 = __shfl(w, i + 1);
            const float w2 = __shfl(w, i + 2), w3 = __shfl(w, i + 3);
            const float v0 = h[(size_t)s0 * HIDDEN + lane];
            const float v1 = h[(size_t)s1 * HIDDEN + lane];
            const float v2 = h[(size_t)s2 * HIDDEN + lane];
            const float v3 = h[(size_t)s3 * HIDDEN + lane];
            a0 = fmaf(v0, w0, a0);
            a1 = fmaf(v1, w1, a1);
            a2 = fmaf(v2, w2, a2);
            a3 = fmaf(v3, w3, a3);
        }
        for (; i < n; ++i) {
            const int si = __shfl(s, i);
            const float wi = __shfl(w, i);
            a0 = fmaf(h[(size_t)si * HIDDEN + lane], wi, a0);
        }
    }
    const float acc = (a0 + a1) + (a2 + a3);
    hn[(size_t)node * HIDDEN + lane] = fmaxf(acc + bias[lane], 0.f);
}

// ---------------------------------------------------------------------------
// K6: global_add_pool — parallel over node chunks. batch is sorted, so each
// wave accumulates locally and flushes one atomic burst per graph switch.
// u must be pre-zeroed.
// ---------------------------------------------------------------------------
__global__ __launch_bounds__(256) void pool_kernel(const float* __restrict__ hn,
                                                   const int* __restrict__ batch,
                                                   float* __restrict__ u) {
    const int chunk = blockIdx.x * 64;
    const int lane = threadIdx.x & 63;
    const int wv = threadIdx.x >> 6;
    const int lim = min(chunk + 64, N_NODES);
    float acc = 0.f;
    int cur_g = -1;
    for (int node = chunk + wv; node < lim; node += 4) {
        const int g = batch[node];
        if (g != cur_g) {
            if (cur_g >= 0) atomicAdd(&u[cur_g * HIDDEN + lane], acc);
            acc = 0.f;
            cur_g = g;
        }
        acc += hn[(size_t)node * HIDDEN + lane];
    }
    if (cur_g >= 0) atomicAdd(&u[cur_g * HIDDEN + lane], acc);
}

// ---------------------------------------------------------------------------
// K7: out[g] = relu(u[g] @ W1 + b1) @ W2 + b2
// ---------------------------------------------------------------------------
__global__ __launch_bounds__(64) void mlp_kernel(const float* __restrict__ u,
                                                 const float* __restrict__ W1,
                                                 const float* __restrict__ b1,
                                                 const float* __restrict__ W2,
                                                 const float* __restrict__ b2,
                                                 float* __restrict__ out) {
    __shared__ float W1s[HIDDEN * 16];
    __shared__ float W2s[16];
    __shared__ float b1s[16];
    const int t = threadIdx.x;
    for (int i = t; i < HIDDEN * 16; i += 64) W1s[i] = W1[i];
    if (t < 16) { W2s[t] = W2[t]; b1s[t] = b1[t]; }
    __syncthreads();
    if (t < NUM_GRAPHS) {
        float uu[HIDDEN];
#pragma unroll
        for (int k = 0; k < HIDDEN; ++k) uu[k] = u[t * HIDDEN + k];
        float o = b2[0];
#pragma unroll
        for (int j = 0; j < 16; ++j) {
            float s = b1s[j];
#pragma unroll
            for (int k = 0; k < HIDDEN; ++k) s = fmaf(uu[k], W1s[k * 16 + j], s);
            o = fmaf(fmaxf(s, 0.f), W2s[j], o);
        }
        out[t] = o;
    }
}

// ---------------------------------------------------------------------------
extern "C" void kernel_launch(void* const* d_in, const int* in_sizes, int n_in,
                              void* d_out, int out_size, void* d_ws, size_t ws_size,
                              hipStream_t stream) {
    const float* x  = (const float*)d_in[0];
    const float* W  = (const float*)d_in[1];
    const float* b  = (const float*)d_in[2];
    const float* W1 = (const float*)d_in[3];
    const float* b1 = (const float*)d_in[4];
    const float* W2 = (const float*)d_in[5];
    const float* b2 = (const float*)d_in[6];
    const int*   ei = (const int*)d_in[7];     // [2, E] flat: src = ei[e], dst = ei[E+e]
    const int* batch = (const int*)d_in[8];    // [N], sorted
    float* out = (float*)d_out;

    // workspace layout:
    //   h       N*64 f32   25.6 MB
    //   hn      N*64 f32   25.6 MB
    //   srcs    E   int     6.4 MB
    //   deg     N   int     0.4 MB
    //   dis     N   f32     0.4 MB
    //   row_ptr N   int     0.4 MB
    //   next    N   int     0.4 MB
    //   bsum/boff/u         tiny
    float* h    = (float*)d_ws;
    float* hn   = h + (size_t)N_NODES * HIDDEN;
    int*   srcs = (int*)(hn + (size_t)N_NODES * HIDDEN);
    int*   deg  = srcs + N_EDGES;
    float* dis  = (float*)(deg + N_NODES);
    int*   row_ptr = (int*)(dis + N_NODES);
    int*   next    = row_ptr + N_NODES;
    int*   bsum    = next + N_NODES;
    int*   boff    = bsum + 512;
    float* u       = (float*)(boff + 512);

    hipMemsetAsync(deg, 0, N_NODES * sizeof(int), stream);
    hipMemsetAsync(u, 0, NUM_GRAPHS * HIDDEN * sizeof(float), stream);

    gemm_xw<<<(N_NODES + 63) / 64, 256, 0, stream>>>(x, W, h);
    deg_kernel<<<(N_EDGES + 255) / 256, 256, 0, stream>>>(ei, deg);
    dis_kernel<<<SCAN_BLOCKS, 256, 0, stream>>>(deg, dis);
    scan1<<<SCAN_BLOCKS, 256, 0, stream>>>(deg, row_ptr, bsum);
    scan2<<<1, 512, 0, stream>>>(bsum, boff);
    scan3<<<SCAN_BLOCKS, 256, 0, stream>>>(row_ptr, boff, next);
    csr_build<<<(N_EDGES + 255) / 256, 256, 0, stream>>>(ei, next, srcs);
    agg_kernel<<<(N_NODES + 3) / 4, 256, 0, stream>>>(row_ptr, next, srcs, h, dis, b, hn);
    pool_kernel<<<(N_NODES + 63) / 64, 256, 0, stream>>>(hn, batch, u);
    mlp_kernel<<<1, 64, 0, stream>>>(u, W1, b1, W2, b2, out);
}

// Round 4
// 356.737 us; speedup vs baseline: 2.0207x; 1.1368x over previous
//
#include <hip/hip_runtime.h>

#define N_NODES   100000
#define N_EDGES   1600000
#define N_FEAT    128
#define HIDDEN    64
#define NUM_GRAPHS 64
#define SCAN_BLOCKS ((N_NODES + 255) / 256)   // 391
#define XPAD 130                              // LDS row stride: bank=(2r+k)%32 -> 2-way (free)
#define N_SHARD 8
#define SHARD_SZ (N_NODES / N_SHARD)          // 12500
#define CSR_CHUNK 8192

// ---------------------------------------------------------------------------
// K1: h = x @ W. lane = row (64 rows/block tile), wave w computes cols
// [16w,16w+16). x staged in LDS (pad 130); W read via wave-uniform scalar
// loads -> SGPR operand of v_fma.
// ---------------------------------------------------------------------------
__global__ __launch_bounds__(256) void gemm_xw(const float* __restrict__ x,
                                               const float* __restrict__ W,
                                               float* __restrict__ h) {
    __shared__ float xs[64 * XPAD];            // 33.3 KB
    const int tid  = threadIdx.x;
    const int lane = tid & 63;
    const int wid  = __builtin_amdgcn_readfirstlane(tid >> 6);  // force wave-uniform
    const int c0   = wid * 16;
    const int base = blockIdx.x * 64;

#pragma unroll
    for (int j = 0; j < 8; ++j) {
        const int flat = (tid + j * 256) * 4;
        const int r = flat >> 7, k = flat & 127;
        const int row = base + r;
        float4 v = make_float4(0.f, 0.f, 0.f, 0.f);
        if (row < N_NODES) v = *(const float4*)&x[(size_t)row * N_FEAT + k];
        xs[r * XPAD + k + 0] = v.x;
        xs[r * XPAD + k + 1] = v.y;
        xs[r * XPAD + k + 2] = v.z;
        xs[r * XPAD + k + 3] = v.w;
    }
    __syncthreads();

    float acc[16];
#pragma unroll
    for (int c = 0; c < 16; ++c) acc[c] = 0.f;

    const float* __restrict__ Wp = W + c0;     // wave-uniform pointer
#pragma unroll 4
    for (int k = 0; k < N_FEAT; ++k) {
        const float xv = xs[lane * XPAD + k];
#pragma unroll
        for (int c = 0; c < 16; ++c)
            acc[c] = fmaf(xv, Wp[k * HIDDEN + c], acc[c]);
    }

    const int row = base + lane;
    if (row < N_NODES) {
        float* hp = &h[(size_t)row * HIDDEN + c0];
#pragma unroll
        for (int c = 0; c < 16; c += 4)
            *(float4*)&hp[c] = make_float4(acc[c], acc[c + 1], acc[c + 2], acc[c + 3]);
    }
}

// ---------------------------------------------------------------------------
// K2: deg[dst] += 1 per edge (deg pre-zeroed; +1 self-loop applied in dis)
// ---------------------------------------------------------------------------
__global__ __launch_bounds__(256) void deg_kernel(const int* __restrict__ ei,
                                                  int* __restrict__ deg) {
    const int e = blockIdx.x * 256 + threadIdx.x;
    if (e < N_EDGES) atomicAdd(&deg[ei[N_EDGES + e]], 1);
}

// ---------------------------------------------------------------------------
// K3: dis[i] = rsqrt(deg[i] + 1)
// ---------------------------------------------------------------------------
__global__ __launch_bounds__(256) void dis_kernel(const int* __restrict__ deg,
                                                  float* __restrict__ dis) {
    const int i = blockIdx.x * 256 + threadIdx.x;
    if (i < N_NODES) dis[i] = rsqrtf((float)deg[i] + 1.0f);
}

// ---------------------------------------------------------------------------
// Scan (exclusive prefix sum of deg -> row_ptr), 3 small kernels.
// ---------------------------------------------------------------------------
__global__ __launch_bounds__(256) void scan1(const int* __restrict__ deg,
                                             int* __restrict__ row_ptr,
                                             int* __restrict__ bsum) {
    __shared__ int s[256];
    const int t = threadIdx.x;
    const int i = blockIdx.x * 256 + t;
    const int v = (i < N_NODES) ? deg[i] : 0;
    s[t] = v;
    __syncthreads();
    for (int off = 1; off < 256; off <<= 1) {
        const int add = (t >= off) ? s[t - off] : 0;
        __syncthreads();
        s[t] += add;
        __syncthreads();
    }
    if (i < N_NODES) row_ptr[i] = s[t] - v;   // exclusive
    if (t == 255) bsum[blockIdx.x] = s[255];
}

__global__ __launch_bounds__(512) void scan2(const int* __restrict__ bsum,
                                             int* __restrict__ boff) {
    __shared__ int s[512];
    const int t = threadIdx.x;
    const int v = (t < SCAN_BLOCKS) ? bsum[t] : 0;
    s[t] = v;
    __syncthreads();
    for (int off = 1; off < 512; off <<= 1) {
        const int add = (t >= off) ? s[t - off] : 0;
        __syncthreads();
        s[t] += add;
        __syncthreads();
    }
    if (t < SCAN_BLOCKS) boff[t] = s[t] - v;  // exclusive
}

__global__ __launch_bounds__(256) void scan3(int* __restrict__ row_ptr,
                                             const int* __restrict__ boff,
                                             int* __restrict__ next) {
    const int i = blockIdx.x * 256 + threadIdx.x;
    if (i < N_NODES) {
        const int r = row_ptr[i] + boff[i >> 8];
        row_ptr[i] = r;
        next[i] = r;
    }
}

// ---------------------------------------------------------------------------
// K4: CSR build, XCD-sharded for L2 write-combining.
// Block b: shard = b&7 (matches blockIdx->XCD round-robin), edge chunk b>>3.
// Each shard's srcs window (~800 KB) is written from one XCD only, so the
// ~16 scattered 4B stores per 64B line combine in that XCD's L2 before
// writeback. Correct regardless of the actual block->XCD mapping (each edge
// is examined by one block per shard, written exactly once).
// ---------------------------------------------------------------------------
__global__ __launch_bounds__(256) void csr_build(const int* __restrict__ ei,
                                                 int* __restrict__ next,
                                                 int* __restrict__ srcs) {
    const int shard = blockIdx.x & (N_SHARD - 1);
    const int base  = (blockIdx.x >> 3) * CSR_CHUNK;
    const int lo = shard * SHARD_SZ;
    const int hi = lo + SHARD_SZ;
    const int lim = min(base + CSR_CHUNK, N_EDGES);
    for (int e = base + threadIdx.x; e < lim; e += 256) {
        const int d = ei[N_EDGES + e];
        if (d >= lo && d < hi) {
            const int s = ei[e];
            const int pos = atomicAdd(&next[d], 1);
            srcs[pos] = s;
        }
    }
}

// ---------------------------------------------------------------------------
// K5: per-node gather-aggregate. One wave per node. Lane L handles edge
// subgroup L>>4, columns (L&15)*4..+3 as float4 (16B/lane gathers). Broadcast
// shuffles amortized to 2 per 4 edges; quarter partials reduced by shfl_xor.
// ---------------------------------------------------------------------------
__global__ __launch_bounds__(256) void agg_kernel(const int* __restrict__ row_ptr,
                                                  const int* __restrict__ row_end,
                                                  const int* __restrict__ srcs,
                                                  const float* __restrict__ h,
                                                  const float* __restrict__ dis,
                                                  const float* __restrict__ bias,
                                                  float* __restrict__ hn) {
    const int node = blockIdx.x * 4 + (threadIdx.x >> 6);
    if (node >= N_NODES) return;
    const int lane = threadIdx.x & 63;
    const int q    = lane >> 4;        // edge subgroup within a 4-edge group
    const int c4   = (lane & 15) * 4;  // column group
    const int beg = row_ptr[node];
    const int end = row_end[node];
    const float dn = dis[node];
    float4 acc = make_float4(0.f, 0.f, 0.f, 0.f);

    for (int j0 = beg; j0 < end; j0 += 64) {
        const int n = min(64, end - j0);
        int s = 0; float w = 0.f;
        if (lane < n) { s = srcs[j0 + lane]; w = dis[s] * dn; }
        const int ng = (n + 3) >> 2;
        for (int i = 0; i < ng; ++i) {
            const int idx = i * 4 + q;          // edge index in chunk (w=0 pads tail)
            const int   si = __shfl(s, idx);
            const float wi = __shfl(w, idx);
            const float4 v = *(const float4*)&h[(size_t)si * HIDDEN + c4];
            acc.x = fmaf(v.x, wi, acc.x);
            acc.y = fmaf(v.y, wi, acc.y);
            acc.z = fmaf(v.z, wi, acc.z);
            acc.w = fmaf(v.w, wi, acc.w);
        }
    }
    // reduce the 4 quarter-partials (lanes c, c+16, c+32, c+48 share columns)
    acc.x += __shfl_xor(acc.x, 16); acc.y += __shfl_xor(acc.y, 16);
    acc.z += __shfl_xor(acc.z, 16); acc.w += __shfl_xor(acc.w, 16);
    acc.x += __shfl_xor(acc.x, 32); acc.y += __shfl_xor(acc.y, 32);
    acc.z += __shfl_xor(acc.z, 32); acc.w += __shfl_xor(acc.w, 32);

    if (lane < 16) {
        const float4 hv = *(const float4*)&h[(size_t)node * HIDDEN + c4];
        const float4 bv = *(const float4*)&bias[c4];
        const float d2 = dn * dn;
        float4 r;
        r.x = fmaxf(fmaf(hv.x, d2, acc.x) + bv.x, 0.f);
        r.y = fmaxf(fmaf(hv.y, d2, acc.y) + bv.y, 0.f);
        r.z = fmaxf(fmaf(hv.z, d2, acc.z) + bv.z, 0.f);
        r.w = fmaxf(fmaf(hv.w, d2, acc.w) + bv.w, 0.f);
        *(float4*)&hn[(size_t)node * HIDDEN + c4] = r;
    }
}

// ---------------------------------------------------------------------------
// K6: global_add_pool — parallel over node chunks; batch sorted, so each wave
// accumulates locally and flushes one atomic burst per graph switch.
// ---------------------------------------------------------------------------
__global__ __launch_bounds__(256) void pool_kernel(const float* __restrict__ hn,
                                                   const int* __restrict__ batch,
                                                   float* __restrict__ u) {
    const int chunk = blockIdx.x * 64;
    const int lane = threadIdx.x & 63;
    const int wv = threadIdx.x >> 6;
    const int lim = min(chunk + 64, N_NODES);
    float acc = 0.f;
    int cur_g = -1;
    for (int node = chunk + wv; node < lim; node += 4) {
        const int g = batch[node];
        if (g != cur_g) {
            if (cur_g >= 0) atomicAdd(&u[cur_g * HIDDEN + lane], acc);
            acc = 0.f;
            cur_g = g;
        }
        acc += hn[(size_t)node * HIDDEN + lane];
    }
    if (cur_g >= 0) atomicAdd(&u[cur_g * HIDDEN + lane], acc);
}

// ---------------------------------------------------------------------------
// K7: out[g] = relu(u[g] @ W1 + b1) @ W2 + b2
// ---------------------------------------------------------------------------
__global__ __launch_bounds__(64) void mlp_kernel(const float* __restrict__ u,
                                                 const float* __restrict__ W1,
                                                 const float* __restrict__ b1,
                                                 const float* __restrict__ W2,
                                                 const float* __restrict__ b2,
                                                 float* __restrict__ out) {
    __shared__ float W1s[HIDDEN * 16];
    __shared__ float W2s[16];
    __shared__ float b1s[16];
    const int t = threadIdx.x;
    for (int i = t; i < HIDDEN * 16; i += 64) W1s[i] = W1[i];
    if (t < 16) { W2s[t] = W2[t]; b1s[t] = b1[t]; }
    __syncthreads();
    if (t < NUM_GRAPHS) {
        float uu[HIDDEN];
#pragma unroll
        for (int k = 0; k < HIDDEN; ++k) uu[k] = u[t * HIDDEN + k];
        float o = b2[0];
#pragma unroll
        for (int j = 0; j < 16; ++j) {
            float s = b1s[j];
#pragma unroll
            for (int k = 0; k < HIDDEN; ++k) s = fmaf(uu[k], W1s[k * 16 + j], s);
            o = fmaf(fmaxf(s, 0.f), W2s[j], o);
        }
        out[t] = o;
    }
}

// ---------------------------------------------------------------------------
extern "C" void kernel_launch(void* const* d_in, const int* in_sizes, int n_in,
                              void* d_out, int out_size, void* d_ws, size_t ws_size,
                              hipStream_t stream) {
    const float* x  = (const float*)d_in[0];
    const float* W  = (const float*)d_in[1];
    const float* b  = (const float*)d_in[2];
    const float* W1 = (const float*)d_in[3];
    const float* b1 = (const float*)d_in[4];
    const float* W2 = (const float*)d_in[5];
    const float* b2 = (const float*)d_in[6];
    const int*   ei = (const int*)d_in[7];     // [2, E] flat: src = ei[e], dst = ei[E+e]
    const int* batch = (const int*)d_in[8];    // [N], sorted
    float* out = (float*)d_out;

    float* h    = (float*)d_ws;
    float* hn   = h + (size_t)N_NODES * HIDDEN;
    int*   srcs = (int*)(hn + (size_t)N_NODES * HIDDEN);
    int*   deg  = srcs + N_EDGES;
    float* dis  = (float*)(deg + N_NODES);
    int*   row_ptr = (int*)(dis + N_NODES);
    int*   next    = row_ptr + N_NODES;
    int*   bsum    = next + N_NODES;
    int*   boff    = bsum + 512;
    float* u       = (float*)(boff + 512);

    hipMemsetAsync(deg, 0, N_NODES * sizeof(int), stream);
    hipMemsetAsync(u, 0, NUM_GRAPHS * HIDDEN * sizeof(float), stream);

    gemm_xw<<<(N_NODES + 63) / 64, 256, 0, stream>>>(x, W, h);
    deg_kernel<<<(N_EDGES + 255) / 256, 256, 0, stream>>>(ei, deg);
    dis_kernel<<<SCAN_BLOCKS, 256, 0, stream>>>(deg, dis);
    scan1<<<SCAN_BLOCKS, 256, 0, stream>>>(deg, row_ptr, bsum);
    scan2<<<1, 512, 0, stream>>>(bsum, boff);
    scan3<<<SCAN_BLOCKS, 256, 0, stream>>>(row_ptr, boff, next);
    csr_build<<<N_SHARD * ((N_EDGES + CSR_CHUNK - 1) / CSR_CHUNK), 256, 0, stream>>>(ei, next, srcs);
    agg_kernel<<<(N_NODES + 3) / 4, 256, 0, stream>>>(row_ptr, next, srcs, h, dis, b, hn);
    pool_kernel<<<(N_NODES + 63) / 64, 256, 0, stream>>>(hn, batch, u);
    mlp_kernel<<<1, 64, 0, stream>>>(u, W1, b1, W2, b2, out);
}